// Round 4
// baseline (268.359 us; speedup 1.0000x reference)
//
#include <hip/hip_runtime.h>
#include <hip/hip_bf16.h>
#include <stdint.h>

typedef unsigned short u16;
typedef __attribute__((ext_vector_type(8))) short bf16x8;   // 8 bf16 = 4 VGPRs
typedef __attribute__((ext_vector_type(4))) float f32x4;

#define DEV __device__ __forceinline__

DEV u16 f2bf(float f) {
  union { float f; unsigned u; } v; v.f = f;
  unsigned r = (v.u + 0x7fffu + ((v.u >> 16) & 1u)) >> 16;   // RNE
  return (u16)r;
}

DEV f32x4 mfma16(bf16x8 a, bf16x8 b, f32x4 c) {
  return __builtin_amdgcn_mfma_f32_16x16x32_bf16(a, b, c, 0, 0, 0);
}

DEV void gload_lds16(const u16* g, u16* l) {
  __builtin_amdgcn_global_load_lds((const __attribute__((address_space(1))) void*)g,
                                   (__attribute__((address_space(3))) void*)l, 16, 0, 0);
}

// softmax logit pre-scale folded into Q: dh^-0.5 (=1/8) * log2(e), so exp = exp2f
#define QSCALE 0.18033688011112042f

// ---------------- fused fp32 -> bf16 convert (+ optional row-major copy) + transpose ----------------
__global__ void cvt_xpose_kernel(const float* __restrict__ src, u16* __restrict__ dst_rm,
                                 u16* __restrict__ dst_tp, int R, int C,
                                 long zS, long zRM, long zTP) {
  __shared__ u16 tile[64][72];
  src += (size_t)blockIdx.z * zS;
  dst_tp += (size_t)blockIdx.z * zTP;
  int r0 = blockIdx.y * 64, c0 = blockIdx.x * 64;
  int tr = threadIdx.x >> 2, tc = (threadIdx.x & 3) * 16;
  const float* s = src + (size_t)(r0 + tr) * C + c0 + tc;
  u16 loc[16];
#pragma unroll
  for (int q = 0; q < 4; ++q) {
    float4 v = ((const float4*)s)[q];
    loc[q * 4 + 0] = f2bf(v.x); loc[q * 4 + 1] = f2bf(v.y);
    loc[q * 4 + 2] = f2bf(v.z); loc[q * 4 + 3] = f2bf(v.w);
  }
#pragma unroll
  for (int i = 0; i < 16; ++i) tile[tr][tc + i] = loc[i];
  if (dst_rm) {
    u16* d = dst_rm + (size_t)blockIdx.z * zRM + (size_t)(r0 + tr) * C + c0 + tc;
    *(bf16x8*)d = *(const bf16x8*)&loc[0];
    *(bf16x8*)(d + 8) = *(const bf16x8*)&loc[8];
  }
  __syncthreads();
  u16 tmp[16];
#pragma unroll
  for (int i = 0; i < 16; ++i) tmp[i] = tile[tc + i][tr];
  u16* d = dst_tp + (size_t)(c0 + tr) * R + r0 + tc;
  *(bf16x8*)d = *(const bf16x8*)&tmp[0];
  *(bf16x8*)(d + 8) = *(const bf16x8*)&tmp[8];
}

// ---------------- 4 weight matrices fp32->bf16 in one launch ----------------
__global__ void cvt_w4_kernel(const float* __restrict__ s0, const float* __restrict__ s1,
                              const float* __restrict__ s2, const float* __restrict__ s3,
                              u16* __restrict__ d0, u16* __restrict__ d1,
                              u16* __restrict__ d2, u16* __restrict__ d3) {
  const float* s; u16* d;
  switch (blockIdx.y) {
    case 0: s = s0; d = d0; break;
    case 1: s = s1; d = d1; break;
    case 2: s = s2; d = d2; break;
    default: s = s3; d = d3; break;
  }
  int i = blockIdx.x * 256 + threadIdx.x;
  float4 v = ((const float4*)s)[i];
  ushort4 o; o.x = f2bf(v.x); o.y = f2bf(v.y); o.z = f2bf(v.z); o.w = f2bf(v.w);
  ((ushort4*)d)[i] = o;
}

// ---------------- split-K reduce ----------------
__global__ void reduce4_kernel(const float* __restrict__ part, u16* __restrict__ out) {
  int i = blockIdx.x * 256 + threadIdx.x;
  const float4* p = (const float4*)part;
  float4 a = p[i], b = p[i + 524288], c = p[i + 1048576], d = p[i + 1572864];
  ushort4 o;
  o.x = f2bf(a.x + b.x + c.x + d.x);
  o.y = f2bf(a.y + b.y + c.y + d.y);
  o.z = f2bf(a.z + b.z + c.z + d.z);
  o.w = f2bf(a.w + b.w + c.w + d.w);
  ((ushort4*)out)[i] = o;
}

// ------------- GEMM: C = A[M][K] * Bt[N][K]^T, bf16 in, fp32 accum -------------
// 128x128 tile, BK=32, 4 waves, double-buffered LDS, XCD swizzle (gx==8).
// launch_bounds(256,5): VGPR~56 easily fits; 5 resident removes the dispatch tail
// (1024-WG grids run as one full round of 4/CU instead of 3+1).
// OMODE: 0 = bf16 out (scaled by cscale), 1 = fp32 + bias, 2 = fp32 raw (split-K partial),
//        3 = kv mode: even z -> bf16 row-major (Cout); odd z -> bf16 TRANSPOSED into CoutT.
template<int OMODE>
__global__ __launch_bounds__(256, 5)
void gemm_bt_kernel(const u16* __restrict__ A, const u16* __restrict__ Bt,
                    const u16* __restrict__ Bt2, void* __restrict__ Cout,
                    u16* __restrict__ CoutT, const float* __restrict__ bias, float cscale,
                    int ldA, int ldB, int ldC, int Klen,
                    long zA, long zB, long zC, int bMod, long kChunk) {
  __shared__ __align__(16) u16 smA[2][128 * 32];
  __shared__ __align__(16) u16 smB[2][128 * 32];
  const int t = threadIdx.x;
  const int lane = t & 63, wave = t >> 6;
  const int wm = wave & 1, wn = wave >> 1;
  const int g = lane >> 4, r = lane & 15;
  const int id = (blockIdx.y << 3) | blockIdx.x;
  const int s = (id & 7) * gridDim.y + (id >> 3);
  const int bx = s & 7, by = s >> 3;
  const int z = blockIdx.z;
  const int b = z % bMod, kc = z / bMod;
  const u16* Ab = A + (size_t)b * zA + (size_t)kc * kChunk;
  const u16* Bbase = (Bt2 && (b & 1)) ? Bt2 : Bt;
  const u16* Bb = Bbase + (size_t)b * zB + (size_t)kc * kChunk;
  const int m0 = by * 128, n0 = bx * 128;
  const int srow = t >> 2;
  const int lslot = ((t & 3) + 4 - ((srow >> 1) & 3)) & 3;

  f32x4 acc[4][4];
#pragma unroll
  for (int m = 0; m < 4; ++m)
#pragma unroll
    for (int n = 0; n < 4; ++n) acc[m][n] = f32x4{0.f, 0.f, 0.f, 0.f};

  auto STAGE = [&](int buf, int k0) {
#pragma unroll
    for (int p = 0; p < 2; ++p) {
      int row = p * 64 + srow;
      gload_lds16(Ab + (size_t)(m0 + row) * ldA + k0 + lslot * 8, &smA[buf][p * 2048 + wave * 512]);
      gload_lds16(Bb + (size_t)(n0 + row) * ldB + k0 + lslot * 8, &smB[buf][p * 2048 + wave * 512]);
    }
  };

  const int nt = Klen >> 5;
  STAGE(0, 0);
  __syncthreads();
  int cur = 0;
  for (int it = 0; it < nt; ++it) {
    if (it + 1 < nt) STAGE(cur ^ 1, (it + 1) << 5);
    bf16x8 af[4], bfr[4];
#pragma unroll
    for (int m = 0; m < 4; ++m) {
      int row = wm * 64 + m * 16 + r;
      int ps = (g + (row >> 1)) & 3;
      af[m] = *(const bf16x8*)&smA[cur][row * 32 + ps * 8];
    }
#pragma unroll
    for (int n = 0; n < 4; ++n) {
      int row = wn * 64 + n * 16 + r;
      int ps = (g + (row >> 1)) & 3;
      bfr[n] = *(const bf16x8*)&smB[cur][row * 32 + ps * 8];
    }
#pragma unroll
    for (int m = 0; m < 4; ++m)
#pragma unroll
      for (int n = 0; n < 4; ++n)
        acc[m][n] = mfma16(af[m], bfr[n], acc[m][n]);
    __syncthreads();
    cur ^= 1;
  }

  // epilogue: C row = (lane>>4)*4+reg, col = lane&15
  if constexpr (OMODE == 0) {
    u16* C = (u16*)Cout + (size_t)z * zC;
#pragma unroll
    for (int n = 0; n < 4; ++n) {
      int col = n0 + wn * 64 + n * 16 + r;
#pragma unroll
      for (int m = 0; m < 4; ++m) {
        int rowb = m0 + wm * 64 + m * 16 + 4 * g;
#pragma unroll
        for (int rr = 0; rr < 4; ++rr)
          C[(size_t)(rowb + rr) * ldC + col] = f2bf(acc[m][n][rr] * cscale);
      }
    }
  } else if constexpr (OMODE == 3) {
    if ((z & 1) == 0) {          // K half: row-major bf16
      u16* C = (u16*)Cout + (size_t)(z >> 1) * zC;
#pragma unroll
      for (int n = 0; n < 4; ++n) {
        int col = n0 + wn * 64 + n * 16 + r;
#pragma unroll
        for (int m = 0; m < 4; ++m) {
          int rowb = m0 + wm * 64 + m * 16 + 4 * g;
#pragma unroll
          for (int rr = 0; rr < 4; ++rr)
            C[(size_t)(rowb + rr) * ldC + col] = f2bf(acc[m][n][rr]);
        }
      }
    } else {                     // V half: transposed bf16, ld = 256
      u16* C = CoutT + (size_t)(z >> 1) * zC;
#pragma unroll
      for (int n = 0; n < 4; ++n) {
        int col = n0 + wn * 64 + n * 16 + r;
#pragma unroll
        for (int m = 0; m < 4; ++m) {
          int rowb = m0 + wm * 64 + m * 16 + 4 * g;
          ushort4 o;
          o.x = f2bf(acc[m][n][0]); o.y = f2bf(acc[m][n][1]);
          o.z = f2bf(acc[m][n][2]); o.w = f2bf(acc[m][n][3]);
          *(ushort4*)&C[(size_t)col * 256 + rowb] = o;
        }
      }
    }
  } else {
    float* C = (float*)Cout + (size_t)z * zC;
#pragma unroll
    for (int n = 0; n < 4; ++n) {
      int col = n0 + wn * 64 + n * 16 + r;
      float bv = (OMODE == 1) ? bias[col] : 0.f;
#pragma unroll
      for (int m = 0; m < 4; ++m) {
        int rowb = m0 + wm * 64 + m * 16 + 4 * g;
#pragma unroll
        for (int rr = 0; rr < 4; ++rr)
          C[(size_t)(rowb + rr) * ldC + col] = acc[m][n][rr] + bv;
      }
    }
  }
}

// ------------- fused attention, swapped-QK^T, all operands in LDS -------------
// Q bf16 (pre-scaled), Kl [4][256][1024], VT [4][1024][256]  (vT[e][k_low]).
// LDS 64 KB: [0:16K) u16 = K[256][64] (slot-rotated), reused as P[64][256] after the
// QK barrier; [16K:32K) u16 = VT[64][256] with col-slot XOR swizzle p^(d&7), staged
// once per WG via global_load_lds with inverse-swizzled global source.
// Softmax lane-local (swapped MFMA); P written normalized, vectorized, wave-private
// rows => no barrier between P write and PV.
__global__ __launch_bounds__(256, 2)
void attn_kernel(const u16* __restrict__ Q, const u16* __restrict__ Kl,
                 const u16* __restrict__ VT, u16* __restrict__ Out) {
  __shared__ __align__(16) u16 sm[32768];   // 64 KB
  const int t = threadIdx.x, lane = t & 63, w = t >> 6;
  const int g = lane >> 4, r = lane & 15;
  const int id = (blockIdx.y << 6) | blockIdx.x;
  const int s = (id & 7) * (gridDim.y << 3) + (id >> 3);
  const int b = blockIdx.z, h = s >> 6, n0 = (s & 63) * 64;
  const u16* Kb = Kl + (size_t)b * 262144 + h * 64;
  const u16* Vb = VT + (size_t)b * 262144 + (size_t)(h * 64) * 256;

  // stage K[256][64], slot rotation phys = (logical + row) & 7
#pragma unroll
  for (int p = 0; p < 8; ++p) {
    int row = p * 32 + (t >> 3);
    int ls = ((t & 7) + 8 - (row & 7)) & 7;
    gload_lds16(Kb + (size_t)row * 1024 + ls * 8, sm + p * 2048 + w * 512);
  }
  // stage VT[64][256]: LDS linear 16B-unit o = i*256+t -> (d=o>>5, physslot=o&31);
  // source col-slot = physslot ^ (d&7)  (both-sides swizzle)
#pragma unroll
  for (int i = 0; i < 8; ++i) {
    int o = i * 256 + t;
    int d = o >> 5, ps = o & 31;
    int sl = ps ^ (d & 7);
    gload_lds16(Vb + (size_t)d * 256 + sl * 8, sm + 16384 + i * 2048 + w * 512);
  }
  const int qrow = n0 + w * 16 + r;
  const u16* Qp = Q + ((size_t)(b * 4096 + qrow)) * 1024 + h * 64 + g * 8;
  bf16x8 aq0 = *(const bf16x8*)Qp;
  bf16x8 aq1 = *(const bf16x8*)(Qp + 32);
  __syncthreads();

  // S^T = mfma(K, Q): lane (g,r) holds S[k=16kf+4g+rr][q=qrow]
  f32x4 dotv[16];
#pragma unroll
  for (int kf = 0; kf < 16; ++kf) {
    int row = kf * 16 + r;
    bf16x8 kb0 = *(const bf16x8*)&sm[row * 64 + ((g + row) & 7) * 8];
    bf16x8 kb1 = *(const bf16x8*)&sm[row * 64 + ((4 + g + row) & 7) * 8];
    f32x4 d = f32x4{0.f, 0.f, 0.f, 0.f};
    d = mfma16(kb0, aq0, d);
    d = mfma16(kb1, aq1, d);
    dotv[kf] = d;
  }
  __syncthreads();   // all waves done reading K; K region becomes P

  // lane-local softmax (combine across g via 2 shfls)
  float mx = -3.4e38f;
#pragma unroll
  for (int kf = 0; kf < 16; ++kf)
    mx = fmaxf(mx, fmaxf(fmaxf(dotv[kf][0], dotv[kf][1]), fmaxf(dotv[kf][2], dotv[kf][3])));
  mx = fmaxf(mx, __shfl_xor(mx, 16, 64));
  mx = fmaxf(mx, __shfl_xor(mx, 32, 64));
  float ssum = 0.f;
#pragma unroll
  for (int kf = 0; kf < 16; ++kf)
#pragma unroll
    for (int j = 0; j < 4; ++j) {
      float p = exp2f(dotv[kf][j] - mx);
      dotv[kf][j] = p;
      ssum += p;
    }
  ssum += __shfl_xor(ssum, 16, 64);
  ssum += __shfl_xor(ssum, 32, 64);
  const float inv = 1.f / ssum;

  // write normalized P (wave-private rows), vectorized b64
  const int q16 = w * 16 + r;
  const int qx = (q16 & 7) << 3;
#pragma unroll
  for (int kf = 0; kf < 16; ++kf) {
    ushort4 pk;
    pk.x = f2bf(dotv[kf][0] * inv); pk.y = f2bf(dotv[kf][1] * inv);
    pk.z = f2bf(dotv[kf][2] * inv); pk.w = f2bf(dotv[kf][3] * inv);
    *(ushort4*)&sm[(q16 * 256 + kf * 16 + 4 * g) ^ qx] = pk;
  }

  // PV: A = own P rows, B = VT from LDS (swizzled)
  f32x4 oacc[4];
#pragma unroll
  for (int df = 0; df < 4; ++df) oacc[df] = f32x4{0.f, 0.f, 0.f, 0.f};
#pragma unroll
  for (int kk = 0; kk < 8; ++kk) {
    bf16x8 ap = *(const bf16x8*)&sm[(q16 * 256 + kk * 32 + g * 8) ^ qx];
#pragma unroll
    for (int df = 0; df < 4; ++df) {
      int d = df * 16 + r;
      bf16x8 bv = *(const bf16x8*)&sm[16384 + d * 256 + (((kk * 4 + g) ^ (d & 7)) << 3)];
      oacc[df] = mfma16(ap, bv, oacc[df]);
    }
  }
#pragma unroll
  for (int df = 0; df < 4; ++df)
#pragma unroll
    for (int rr = 0; rr < 4; ++rr) {
      int orow = n0 + w * 16 + 4 * g + rr;
      int ocol = h * 64 + df * 16 + r;
      Out[((size_t)(b * 4096 + orow)) * 1024 + ocol] = f2bf(oacc[df][rr]);
    }
}

extern "C" void kernel_launch(void* const* d_in, const int* in_sizes, int n_in,
                              void* d_out, int out_size, void* d_ws, size_t ws_size,
                              hipStream_t stream) {
  const float* x  = (const float*)d_in[0];
  const float* Wq = (const float*)d_in[1];
  const float* Wk = (const float*)d_in[2];
  const float* Wv = (const float*)d_in[3];
  const float* pk = (const float*)d_in[4];
  const float* pv = (const float*)d_in[5];
  const float* Wo = (const float*)d_in[6];
  const float* bo = (const float*)d_in[7];

  u16* ws = (u16*)d_ws;
  u16* xbf   = ws;                   // [4][4096][1024]
  u16* xT    = xbf + 16777216;       // [4][1024][4096]
  u16* wqb   = xT + 16777216;        // [1024][1024]
  u16* wkb   = wqb + 1048576;
  u16* wvb   = wkb + 1048576;
  u16* wob   = wvb + 1048576;
  u16* projT = wob + 1048576;        // [2][256][4096]
  u16* Qb    = projT + 2097152;      // [16384][1024]; holds xp fp32 partials first
  u16* xp    = Qb + 16777216;        // [4][512][1024]
  u16* klow  = xp + 2097152;         // [4][256][1024]
  u16* vT    = klow + 1048576;       // [4][1024][256]
  u16* aout  = xbf;                  // reuse after Q GEMM
  float* xp_part = (float*)Qb;       // [4 kc][4 b][512][1024] fp32

  // 1) x: convert + row-major bf16 + transpose (one read of x)
  cvt_xpose_kernel<<<dim3(16, 64, 4), 256, 0, stream>>>(x, xbf, xT, 4096, 1024,
                                                        4194304, 4194304, 4194304);
  // 2) weights
  cvt_w4_kernel<<<dim3(1024, 4), 256, 0, stream>>>(Wq, Wk, Wv, Wo, wqb, wkb, wvb, wob);
  // 3) proj transposes
  cvt_xpose_kernel<<<dim3(4, 64, 1), 256, 0, stream>>>(pk, nullptr, projT, 4096, 256, 0, 0, 0);
  cvt_xpose_kernel<<<dim3(4, 64, 1), 256, 0, stream>>>(pv, nullptr, projT + 1048576, 4096, 256, 0, 0, 0);
  // 4) xp partials: split-K x4, z = kc*4 + b
  gemm_bt_kernel<2><<<dim3(8, 4, 16), 256, 0, stream>>>(
      projT, xT, nullptr, (void*)xp_part, nullptr, nullptr, 1.f,
      4096, 4096, 1024, 1024, 0, 4194304, 524288, 4, 1024);
  // 5) reduce partials -> xp bf16
  reduce4_kernel<<<2048, 256, 0, stream>>>(xp_part, xp);
  // 6) kv: z = b'*2 + half; K half -> klow row-major, V half -> vT transposed
  gemm_bt_kernel<3><<<dim3(8, 2, 8), 256, 0, stream>>>(
      xp, wkb, wvb, (void*)klow, vT, nullptr, 1.f,
      1024, 1024, 1024, 1024, 262144, 0, 262144, 8, 0);
  // 7) Q = (x @ Wq^T) * QSCALE  (xp_part dead -> Qb free)
  gemm_bt_kernel<0><<<dim3(8, 128, 1), 256, 0, stream>>>(
      xbf, wqb, nullptr, (void*)Qb, nullptr, nullptr, QSCALE,
      1024, 1024, 1024, 1024, 0, 0, 0, 1, 0);
  // 8) attention
  attn_kernel<<<dim3(64, 16, 4), 256, 0, stream>>>(Qb, klow, vT, aout);
  // 9) final = attn_out @ Wo^T + bo -> fp32 d_out
  gemm_bt_kernel<1><<<dim3(8, 128, 1), 256, 0, stream>>>(
      aout, wob, nullptr, d_out, nullptr, bo, 1.f,
      1024, 1024, 1024, 1024, 0, 0, 0, 1, 0);
}

// Round 5
// 221.740 us; speedup vs baseline: 1.2102x; 1.2102x over previous
//
#include <hip/hip_runtime.h>
#include <hip/hip_bf16.h>
#include <stdint.h>

typedef unsigned short u16;
typedef __attribute__((ext_vector_type(8))) short bf16x8;   // 8 bf16 = 4 VGPRs
typedef __attribute__((ext_vector_type(4))) float f32x4;

#define DEV __device__ __forceinline__

DEV u16 f2bf(float f) {
  union { float f; unsigned u; } v; v.f = f;
  unsigned r = (v.u + 0x7fffu + ((v.u >> 16) & 1u)) >> 16;   // RNE
  return (u16)r;
}

// packed 2x f32 -> 2x bf16 (v_cvt_pk_bf16_f32), RNE
DEV unsigned pk2(float lo, float hi) {
  union { __hip_bfloat162 h; unsigned u; } c;
  c.h = __float22bfloat162_rn(make_float2(lo, hi));
  return c.u;
}

DEV f32x4 mfma16(bf16x8 a, bf16x8 b, f32x4 c) {
  return __builtin_amdgcn_mfma_f32_16x16x32_bf16(a, b, c, 0, 0, 0);
}

DEV void gload_lds16(const u16* g, u16* l) {
  __builtin_amdgcn_global_load_lds((const __attribute__((address_space(1))) void*)g,
                                   (__attribute__((address_space(3))) void*)l, 16, 0, 0);
}

// softmax logit pre-scale folded into Q: dh^-0.5 (=1/8) * log2(e), so exp = exp2f
#define QSCALE 0.18033688011112042f

// ---------------- fused fp32 -> bf16 convert (+ optional row-major copy) + transpose ----------------
__global__ void cvt_xpose_kernel(const float* __restrict__ src, u16* __restrict__ dst_rm,
                                 u16* __restrict__ dst_tp, int R, int C,
                                 long zS, long zRM, long zTP) {
  __shared__ u16 tile[64][72];
  src += (size_t)blockIdx.z * zS;
  dst_tp += (size_t)blockIdx.z * zTP;
  int r0 = blockIdx.y * 64, c0 = blockIdx.x * 64;
  int tr = threadIdx.x >> 2, tc = (threadIdx.x & 3) * 16;
  const float* s = src + (size_t)(r0 + tr) * C + c0 + tc;
  u16 loc[16];
#pragma unroll
  for (int q = 0; q < 4; ++q) {
    float4 v = ((const float4*)s)[q];
    loc[q * 4 + 0] = f2bf(v.x); loc[q * 4 + 1] = f2bf(v.y);
    loc[q * 4 + 2] = f2bf(v.z); loc[q * 4 + 3] = f2bf(v.w);
  }
#pragma unroll
  for (int i = 0; i < 16; ++i) tile[tr][tc + i] = loc[i];
  if (dst_rm) {
    u16* d = dst_rm + (size_t)blockIdx.z * zRM + (size_t)(r0 + tr) * C + c0 + tc;
    *(bf16x8*)d = *(const bf16x8*)&loc[0];
    *(bf16x8*)(d + 8) = *(const bf16x8*)&loc[8];
  }
  __syncthreads();
  u16 tmp[16];
#pragma unroll
  for (int i = 0; i < 16; ++i) tmp[i] = tile[tc + i][tr];
  u16* d = dst_tp + (size_t)(c0 + tr) * R + r0 + tc;
  *(bf16x8*)d = *(const bf16x8*)&tmp[0];
  *(bf16x8*)(d + 8) = *(const bf16x8*)&tmp[8];
}

// ---------------- 4 weight matrices fp32->bf16 in one launch ----------------
__global__ void cvt_w4_kernel(const float* __restrict__ s0, const float* __restrict__ s1,
                              const float* __restrict__ s2, const float* __restrict__ s3,
                              u16* __restrict__ d0, u16* __restrict__ d1,
                              u16* __restrict__ d2, u16* __restrict__ d3) {
  const float* s; u16* d;
  switch (blockIdx.y) {
    case 0: s = s0; d = d0; break;
    case 1: s = s1; d = d1; break;
    case 2: s = s2; d = d2; break;
    default: s = s3; d = d3; break;
  }
  int i = blockIdx.x * 256 + threadIdx.x;
  float4 v = ((const float4*)s)[i];
  ushort4 o; o.x = f2bf(v.x); o.y = f2bf(v.y); o.z = f2bf(v.z); o.w = f2bf(v.w);
  ((ushort4*)d)[i] = o;
}

// ---------------- split-K reduce ----------------
__global__ void reduce4_kernel(const float* __restrict__ part, u16* __restrict__ out) {
  int i = blockIdx.x * 256 + threadIdx.x;
  const float4* p = (const float4*)part;
  float4 a = p[i], b = p[i + 524288], c = p[i + 1048576], d = p[i + 1572864];
  ushort4 o;
  o.x = f2bf(a.x + b.x + c.x + d.x);
  o.y = f2bf(a.y + b.y + c.y + d.y);
  o.z = f2bf(a.z + b.z + c.z + d.z);
  o.w = f2bf(a.w + b.w + c.w + d.w);
  ((ushort4*)out)[i] = o;
}

// ------------- GEMM: C = A[M][K] * Bt[N][K]^T, bf16 in, fp32 accum -------------
// 128x128 tile, BK=32, 4 waves, double-buffered LDS, XCD swizzle (gx==8).
// launch_bounds(256,4): VGPR cap 128 >= ~120 needed (56 arch + 64 acc), no spill;
// 1024-WG grids run as exactly one 4/CU round (no tail).  (256,5) spilled: R4 lesson.
// OMODE: 0 = bf16 out (scaled by cscale), 1 = fp32 + bias, 2 = fp32 raw (split-K partial),
//        3 = kv mode: even z -> bf16 row-major (Cout); odd z -> bf16 TRANSPOSED into CoutT.
template<int OMODE>
__global__ __launch_bounds__(256, 4)
void gemm_bt_kernel(const u16* __restrict__ A, const u16* __restrict__ Bt,
                    const u16* __restrict__ Bt2, void* __restrict__ Cout,
                    u16* __restrict__ CoutT, const float* __restrict__ bias, float cscale,
                    int ldA, int ldB, int ldC, int Klen,
                    long zA, long zB, long zC, int bMod, long kChunk) {
  __shared__ __align__(16) u16 smA[2][128 * 32];
  __shared__ __align__(16) u16 smB[2][128 * 32];
  const int t = threadIdx.x;
  const int lane = t & 63, wave = t >> 6;
  const int wm = wave & 1, wn = wave >> 1;
  const int g = lane >> 4, r = lane & 15;
  const int id = (blockIdx.y << 3) | blockIdx.x;
  const int s = (id & 7) * gridDim.y + (id >> 3);
  const int bx = s & 7, by = s >> 3;
  const int z = blockIdx.z;
  const int b = z % bMod, kc = z / bMod;
  const u16* Ab = A + (size_t)b * zA + (size_t)kc * kChunk;
  const u16* Bbase = (Bt2 && (b & 1)) ? Bt2 : Bt;
  const u16* Bb = Bbase + (size_t)b * zB + (size_t)kc * kChunk;
  const int m0 = by * 128, n0 = bx * 128;
  const int srow = t >> 2;
  const int lslot = ((t & 3) + 4 - ((srow >> 1) & 3)) & 3;

  f32x4 acc[4][4];
#pragma unroll
  for (int m = 0; m < 4; ++m)
#pragma unroll
    for (int n = 0; n < 4; ++n) acc[m][n] = f32x4{0.f, 0.f, 0.f, 0.f};

  auto STAGE = [&](int buf, int k0) {
#pragma unroll
    for (int p = 0; p < 2; ++p) {
      int row = p * 64 + srow;
      gload_lds16(Ab + (size_t)(m0 + row) * ldA + k0 + lslot * 8, &smA[buf][p * 2048 + wave * 512]);
      gload_lds16(Bb + (size_t)(n0 + row) * ldB + k0 + lslot * 8, &smB[buf][p * 2048 + wave * 512]);
    }
  };

  const int nt = Klen >> 5;
  STAGE(0, 0);
  __syncthreads();
  int cur = 0;
  for (int it = 0; it < nt; ++it) {
    if (it + 1 < nt) STAGE(cur ^ 1, (it + 1) << 5);
    bf16x8 af[4], bfr[4];
#pragma unroll
    for (int m = 0; m < 4; ++m) {
      int row = wm * 64 + m * 16 + r;
      int ps = (g + (row >> 1)) & 3;
      af[m] = *(const bf16x8*)&smA[cur][row * 32 + ps * 8];
    }
#pragma unroll
    for (int n = 0; n < 4; ++n) {
      int row = wn * 64 + n * 16 + r;
      int ps = (g + (row >> 1)) & 3;
      bfr[n] = *(const bf16x8*)&smB[cur][row * 32 + ps * 8];
    }
#pragma unroll
    for (int m = 0; m < 4; ++m)
#pragma unroll
      for (int n = 0; n < 4; ++n)
        acc[m][n] = mfma16(af[m], bfr[n], acc[m][n]);
    __syncthreads();
    cur ^= 1;
  }

  // epilogue: C row = (lane>>4)*4+reg, col = lane&15
  if constexpr (OMODE == 0) {
    u16* C = (u16*)Cout + (size_t)z * zC;
#pragma unroll
    for (int n = 0; n < 4; ++n) {
      int col = n0 + wn * 64 + n * 16 + r;
#pragma unroll
      for (int m = 0; m < 4; ++m) {
        int rowb = m0 + wm * 64 + m * 16 + 4 * g;
#pragma unroll
        for (int rr = 0; rr < 4; ++rr)
          C[(size_t)(rowb + rr) * ldC + col] = f2bf(acc[m][n][rr] * cscale);
      }
    }
  } else if constexpr (OMODE == 3) {
    if ((z & 1) == 0) {          // K half: row-major bf16
      u16* C = (u16*)Cout + (size_t)(z >> 1) * zC;
#pragma unroll
      for (int n = 0; n < 4; ++n) {
        int col = n0 + wn * 64 + n * 16 + r;
#pragma unroll
        for (int m = 0; m < 4; ++m) {
          int rowb = m0 + wm * 64 + m * 16 + 4 * g;
#pragma unroll
          for (int rr = 0; rr < 4; ++rr)
            C[(size_t)(rowb + rr) * ldC + col] = f2bf(acc[m][n][rr]);
        }
      }
    } else {                     // V half: transposed bf16, ld = 256
      u16* C = CoutT + (size_t)(z >> 1) * zC;
#pragma unroll
      for (int n = 0; n < 4; ++n) {
        int col = n0 + wn * 64 + n * 16 + r;
#pragma unroll
        for (int m = 0; m < 4; ++m) {
          int rowb = m0 + wm * 64 + m * 16 + 4 * g;
          ushort4 o;
          o.x = f2bf(acc[m][n][0]); o.y = f2bf(acc[m][n][1]);
          o.z = f2bf(acc[m][n][2]); o.w = f2bf(acc[m][n][3]);
          *(ushort4*)&C[(size_t)col * 256 + rowb] = o;
        }
      }
    }
  } else {
    float* C = (float*)Cout + (size_t)z * zC;
#pragma unroll
    for (int n = 0; n < 4; ++n) {
      int col = n0 + wn * 64 + n * 16 + r;
      float bv = (OMODE == 1) ? bias[col] : 0.f;
#pragma unroll
      for (int m = 0; m < 4; ++m) {
        int rowb = m0 + wm * 64 + m * 16 + 4 * g;
#pragma unroll
        for (int rr = 0; rr < 4; ++rr)
          C[(size_t)(rowb + rr) * ldC + col] = acc[m][n][rr] + bv;
      }
    }
  }
}

// ------------- fused attention, swapped-QK^T, k-sliced VT -------------
// Q bf16 (pre-scaled), Kl [4][256][1024], VT [4][1024][256].
// LDS 40 KB: [0:16384) u16 = K[256][64] (slot-rotated), reused as P[64][256] after the
// QK barrier; [16384:20480) u16 = VT k-slice double buffer, 2 x [64][32] (4 KB each),
// staged one slice ahead inside the PV loop (stage issued AFTER the barrier that
// retires the buffer; consumed after the next barrier). 40 KB -> 4 WG/CU.
__global__ __launch_bounds__(256, 4)
void attn_kernel(const u16* __restrict__ Q, const u16* __restrict__ Kl,
                 const u16* __restrict__ VT, u16* __restrict__ Out) {
  __shared__ __align__(16) u16 sm[20480];   // 40 KB
  const int t = threadIdx.x, lane = t & 63, w = t >> 6;
  const int g = lane >> 4, r = lane & 15;
  const int id = (blockIdx.y << 6) | blockIdx.x;
  const int s = (id & 7) * (gridDim.y << 3) + (id >> 3);
  const int b = blockIdx.z, h = s >> 6, n0 = (s & 63) * 64;
  const u16* Kb = Kl + (size_t)b * 262144 + h * 64;
  const u16* Vb = VT + (size_t)b * 262144 + (size_t)(h * 64) * 256;
  u16* vbase = sm + 16384;

  // VT slice stage: thread t handles unit (d = t>>2, slot = t&3) of slice kk;
  // col-slot XOR swizzle sl = (t&3)^(d&3) on the GLOBAL side, linear LDS dest.
  const int vd = t >> 2;
  const int vsl = (t & 3) ^ (vd & 3);
  auto stage_slice = [&](int kk, int buf) {
    gload_lds16(Vb + (size_t)vd * 256 + kk * 32 + vsl * 8, vbase + buf * 2048 + w * 512);
  };

  // stage K[256][64], slot rotation phys = (logical + row) & 7
#pragma unroll
  for (int p = 0; p < 8; ++p) {
    int row = p * 32 + (t >> 3);
    int ls = ((t & 7) + 8 - (row & 7)) & 7;
    gload_lds16(Kb + (size_t)row * 1024 + ls * 8, sm + p * 2048 + w * 512);
  }
  stage_slice(0, 0);
  stage_slice(1, 1);
  const int qrow = n0 + w * 16 + r;
  const u16* Qp = Q + ((size_t)(b * 4096 + qrow)) * 1024 + h * 64 + g * 8;
  bf16x8 aq0 = *(const bf16x8*)Qp;
  bf16x8 aq1 = *(const bf16x8*)(Qp + 32);
  __syncthreads();   // (1) K + slices 0,1 ready

  // S^T = mfma(K, Q): lane (g,r) holds S[k=16kf+4g+rr][q=qrow]
  f32x4 dotv[16];
#pragma unroll
  for (int kf = 0; kf < 16; ++kf) {
    int row = kf * 16 + r;
    bf16x8 kb0 = *(const bf16x8*)&sm[row * 64 + ((g + row) & 7) * 8];
    bf16x8 kb1 = *(const bf16x8*)&sm[row * 64 + ((4 + g + row) & 7) * 8];
    f32x4 d = f32x4{0.f, 0.f, 0.f, 0.f};
    d = mfma16(kb0, aq0, d);
    d = mfma16(kb1, aq1, d);
    dotv[kf] = d;
  }
  __syncthreads();   // (2) all QK reads done; K region becomes P

  // lane-local softmax (combine across g via 2 shfls)
  float mx = -3.4e38f;
#pragma unroll
  for (int kf = 0; kf < 16; ++kf)
    mx = fmaxf(mx, fmaxf(fmaxf(dotv[kf][0], dotv[kf][1]), fmaxf(dotv[kf][2], dotv[kf][3])));
  mx = fmaxf(mx, __shfl_xor(mx, 16, 64));
  mx = fmaxf(mx, __shfl_xor(mx, 32, 64));
  float ssum = 0.f;
#pragma unroll
  for (int kf = 0; kf < 16; ++kf)
#pragma unroll
    for (int j = 0; j < 4; ++j) {
      float p = exp2f(dotv[kf][j] - mx);
      dotv[kf][j] = p;
      ssum += p;
    }
  ssum += __shfl_xor(ssum, 16, 64);
  ssum += __shfl_xor(ssum, 32, 64);
  const float inv = 1.f / ssum;

  // write normalized P (wave-private rows), packed cvt + b64 writes
  const int q16 = w * 16 + r;
  const int qx = (q16 & 7) << 3;
#pragma unroll
  for (int kf = 0; kf < 16; ++kf) {
    uint2 val;
    val.x = pk2(dotv[kf][0] * inv, dotv[kf][1] * inv);
    val.y = pk2(dotv[kf][2] * inv, dotv[kf][3] * inv);
    *(uint2*)&sm[(q16 * 256 + kf * 16 + 4 * g) ^ qx] = val;
  }

  // PV: A = own P rows (no barrier needed), B = VT slice dbuf
  f32x4 oacc[4];
#pragma unroll
  for (int df = 0; df < 4; ++df) oacc[df] = f32x4{0.f, 0.f, 0.f, 0.f};
#pragma unroll
  for (int kk = 0; kk < 8; ++kk) {
    bf16x8 ap = *(const bf16x8*)&sm[(q16 * 256 + kk * 32 + g * 8) ^ qx];
    const u16* vb = vbase + (kk & 1) * 2048;
#pragma unroll
    for (int df = 0; df < 4; ++df) {
      int d = df * 16 + r;
      bf16x8 bv = *(const bf16x8*)&vb[d * 32 + (g ^ (d & 3)) * 8];
      oacc[df] = mfma16(ap, bv, oacc[df]);
    }
    if (kk < 7) {
      __syncthreads();             // slice kk+1 ready; buffer kk&1 retired by all waves
      if (kk < 6) stage_slice(kk + 2, kk & 1);
    }
  }
#pragma unroll
  for (int df = 0; df < 4; ++df)
#pragma unroll
    for (int rr = 0; rr < 4; ++rr) {
      int orow = n0 + w * 16 + 4 * g + rr;
      int ocol = h * 64 + df * 16 + r;
      Out[((size_t)(b * 4096 + orow)) * 1024 + ocol] = f2bf(oacc[df][rr]);
    }
}

extern "C" void kernel_launch(void* const* d_in, const int* in_sizes, int n_in,
                              void* d_out, int out_size, void* d_ws, size_t ws_size,
                              hipStream_t stream) {
  const float* x  = (const float*)d_in[0];
  const float* Wq = (const float*)d_in[1];
  const float* Wk = (const float*)d_in[2];
  const float* Wv = (const float*)d_in[3];
  const float* pk = (const float*)d_in[4];
  const float* pv = (const float*)d_in[5];
  const float* Wo = (const float*)d_in[6];
  const float* bo = (const float*)d_in[7];

  u16* ws = (u16*)d_ws;
  u16* xbf   = ws;                   // [4][4096][1024]
  u16* xT    = xbf + 16777216;       // [4][1024][4096]
  u16* wqb   = xT + 16777216;        // [1024][1024]
  u16* wkb   = wqb + 1048576;
  u16* wvb   = wkb + 1048576;
  u16* wob   = wvb + 1048576;
  u16* projT = wob + 1048576;        // [2][256][4096]
  u16* Qb    = projT + 2097152;      // [16384][1024]; holds xp fp32 partials first
  u16* xp    = Qb + 16777216;        // [4][512][1024]
  u16* klow  = xp + 2097152;         // [4][256][1024]
  u16* vT    = klow + 1048576;       // [4][1024][256]
  u16* aout  = xbf;                  // reuse after Q GEMM
  float* xp_part = (float*)Qb;       // [4 kc][4 b][512][1024] fp32

  // 1) x: convert + row-major bf16 + transpose (one read of x)
  cvt_xpose_kernel<<<dim3(16, 64, 4), 256, 0, stream>>>(x, xbf, xT, 4096, 1024,
                                                        4194304, 4194304, 4194304);
  // 2) weights
  cvt_w4_kernel<<<dim3(1024, 4), 256, 0, stream>>>(Wq, Wk, Wv, Wo, wqb, wkb, wvb, wob);
  // 3) proj transposes
  cvt_xpose_kernel<<<dim3(4, 64, 1), 256, 0, stream>>>(pk, nullptr, projT, 4096, 256, 0, 0, 0);
  cvt_xpose_kernel<<<dim3(4, 64, 1), 256, 0, stream>>>(pv, nullptr, projT + 1048576, 4096, 256, 0, 0, 0);
  // 4) xp partials: split-K x4, z = kc*4 + b
  gemm_bt_kernel<2><<<dim3(8, 4, 16), 256, 0, stream>>>(
      projT, xT, nullptr, (void*)xp_part, nullptr, nullptr, 1.f,
      4096, 4096, 1024, 1024, 0, 4194304, 524288, 4, 1024);
  // 5) reduce partials -> xp bf16
  reduce4_kernel<<<2048, 256, 0, stream>>>(xp_part, xp);
  // 6) kv: z = b'*2 + half; K half -> klow row-major, V half -> vT transposed
  gemm_bt_kernel<3><<<dim3(8, 2, 8), 256, 0, stream>>>(
      xp, wkb, wvb, (void*)klow, vT, nullptr, 1.f,
      1024, 1024, 1024, 1024, 262144, 0, 262144, 8, 0);
  // 7) Q = (x @ Wq^T) * QSCALE  (xp_part dead -> Qb free)
  gemm_bt_kernel<0><<<dim3(8, 128, 1), 256, 0, stream>>>(
      xbf, wqb, nullptr, (void*)Qb, nullptr, nullptr, QSCALE,
      1024, 1024, 1024, 1024, 0, 0, 0, 1, 0);
  // 8) attention
  attn_kernel<<<dim3(64, 16, 4), 256, 0, stream>>>(Qb, klow, vT, aout);
  // 9) final = attn_out @ Wo^T + bo -> fp32 d_out
  gemm_bt_kernel<1><<<dim3(8, 128, 1), 256, 0, stream>>>(
      aout, wob, nullptr, d_out, nullptr, bo, 1.f,
      1024, 1024, 1024, 1024, 0, 0, 0, 1, 0);
}